// Round 5
// baseline (279.579 us; speedup 1.0000x reference)
//
#include <hip/hip_runtime.h>

typedef unsigned short ushort_t;
typedef short s16x8 __attribute__((ext_vector_type(8)));
typedef float f32x4 __attribute__((ext_vector_type(4)));

#define MFMA16(a, b, c) __builtin_amdgcn_mfma_f32_16x16x32_bf16((a), (b), (c), 0, 0, 0)

// ---- sizes ----
#define BATCH 16
#define N1 1024
#define C1 256
#define N2 256
#define N3 64
// proj block counts: f3 16-row, f2 16-row, f1 32-row
#define PB3 64
#define PB2 256
#define PB1 512
// LDS transpose stride (ushorts): 40*2=80 B (16B-aligned for uint4)
#define TST 40

// float -> bf16 bits, round-to-nearest-even
static __device__ __forceinline__ ushort_t f2b(float f) {
    unsigned int u = __builtin_bit_cast(unsigned int, f);
    unsigned int r = (u + 0x7fffu + ((u >> 16) & 1u)) >> 16;
    return (ushort_t)r;
}
static __device__ __forceinline__ float b2f(ushort_t b) {
    unsigned int u = ((unsigned int)b) << 16;
    return __builtin_bit_cast(float, u);
}

static __device__ __forceinline__ s16x8 cvt8(const float* p) {
    f32x4 lo = *reinterpret_cast<const f32x4*>(p);
    f32x4 hi = *reinterpret_cast<const f32x4*>(p + 4);
    s16x8 r;
#pragma unroll
    for (int i = 0; i < 4; ++i) {
        r[i]     = (short)f2b(lo[i]);
        r[i + 4] = (short)f2b(hi[i]);
    }
    return r;
}

// ---- merged transpose+convert of weights: wt[d][k] = bf16(w[k][d]) ----
__global__ void k_wt(const float* __restrict__ w1, const float* __restrict__ w2,
                     const float* __restrict__ w3,
                     ushort_t* __restrict__ w1t, ushort_t* __restrict__ w2t,
                     ushort_t* __restrict__ w3t) {
    int i = blockIdx.x * 256 + threadIdx.x;
    if (i < 65536) {
        int d = i >> 8, k = i & 255;
        w1t[i] = f2b(w1[k * 256 + d]);
    } else if (i < 65536 + 131072) {
        int j = i - 65536;
        int d = j >> 9, k = j & 511;
        w2t[j] = f2b(w2[k * 256 + d]);
    } else if (i < 65536 + 131072 + 262144) {
        int j = i - 65536 - 131072;
        int d = j >> 10, k = j & 1023;
        w3t[j] = f2b(w3[k * 256 + d]);
    }
}

// 16-row x 256-col projection tile, compile-time K (unrollable / pipelined)
template <int K>
static __device__ __forceinline__ void proj16(
    const float* __restrict__ A, const ushort_t* __restrict__ wt,
    const float* __restrict__ bias, ushort_t* __restrict__ xb,
    int tile, int w, int lr, int lk)
{
    int rowBase = tile * 16;
    const float* arow = A + (size_t)(rowBase + lr) * K + lk;
    f32x4 acc[4] = {};
#pragma unroll 4
    for (int kk = 0; kk < K; kk += 32) {
        s16x8 af = cvt8(arow + kk);
#pragma unroll
        for (int t = 0; t < 4; ++t) {
            const ushort_t* bp = wt + (size_t)(w * 64 + t * 16 + lr) * K + kk + lk;
            acc[t] = MFMA16(af, *reinterpret_cast<const s16x8*>(bp), acc[t]);
        }
    }
    int r0 = rowBase + (lk >> 3) * 4;
#pragma unroll
    for (int t = 0; t < 4; ++t) {
        int c = w * 64 + t * 16 + lr;
        float bs = bias[c];
#pragma unroll
        for (int j = 0; j < 4; ++j)
            xb[(size_t)(r0 + j) * 256 + c] = f2b(acc[t][j] + bs);
    }
}

// ---- merged projection GEMM ----
__global__ __launch_bounds__(256) void k_proj(
    const float* __restrict__ f1, const float* __restrict__ f2,
    const float* __restrict__ f3,
    const ushort_t* __restrict__ w1t, const ushort_t* __restrict__ w2t,
    const ushort_t* __restrict__ w3t,
    const float* __restrict__ b1, const float* __restrict__ b2,
    const float* __restrict__ b3,
    ushort_t* __restrict__ x1b, ushort_t* __restrict__ x1t,
    ushort_t* __restrict__ x2b, ushort_t* __restrict__ x3b)
{
    __shared__ ushort_t sT[256 * TST];   // 20.5 KB (f1 path only)

    int bid = blockIdx.x;
    int w = threadIdx.x >> 6, l = threadIdx.x & 63;
    int lr = l & 15, g = l >> 4, lk = g * 8;

    if (bid < PB3) {
        proj16<1024>(f3, w3t, b3, x3b, bid, w, lr, lk);
    } else if (bid < PB3 + PB2) {
        proj16<512>(f2, w2t, b2, x2b, bid - PB3, w, lr, lk);
    } else {
        // f1: 32 rows x 256 cols; wave w: rows (w&1)*16, cols (w>>1)*128
        int tile = bid - PB3 - PB2;
        int rowBase = tile * 32;
        int rowHalf = w & 1, colHalf = w >> 1;
        const float* arow = f1 + (size_t)(rowBase + rowHalf * 16 + lr) * 256 + lk;

        f32x4 acc[8] = {};
#pragma unroll 2
        for (int kk = 0; kk < 256; kk += 32) {
            s16x8 af = cvt8(arow + kk);
#pragma unroll
            for (int t = 0; t < 8; ++t) {
                const ushort_t* bp = w1t + (size_t)(colHalf * 128 + t * 16 + lr) * 256 + kk + lk;
                acc[t] = MFMA16(af, *reinterpret_cast<const s16x8*>(bp), acc[t]);
            }
        }
        int rl0 = rowHalf * 16 + g * 4;
#pragma unroll
        for (int t = 0; t < 8; ++t) {
            int c = colHalf * 128 + t * 16 + lr;
            float bs = b1[c];
#pragma unroll
            for (int j = 0; j < 4; ++j) {
                float v = acc[t][j] + bs;
                ushort_t bits = f2b(v);
                x1b[(size_t)(rowBase + rl0 + j) * 256 + c] = bits;
                sT[c * TST + rl0 + j] = bits;
            }
        }
        __syncthreads();
        // coalesced x1t write: thread t -> col t, 32 rows = 64B = 4x uint4
        int b = rowBase >> 10, mBase = rowBase & 1023;
        int c = threadIdx.x;
        const uint4* src = reinterpret_cast<const uint4*>(&sT[c * TST]);
        uint4* dst = reinterpret_cast<uint4*>(&x1t[(((size_t)b * 256 + c) << 10) + mBase]);
#pragma unroll
        for (int q = 0; q < 4; ++q) dst[q] = src[q];
    }
}

// ---- merged Gram matrices ----
__global__ __launch_bounds__(256) void k_xxt(
    const ushort_t* __restrict__ x2b, const ushort_t* __restrict__ x3b,
    float* __restrict__ att2, float* __restrict__ att3)
{
    int bid = blockIdx.x;
    const ushort_t* x; float* att; int n, b, bx, by;
    if (bid < 16) { x = x3b; att = att3; n = 64; b = bid; bx = 0; by = 0; }
    else {
        int j = bid - 16;
        x = x2b; att = att2; n = 256;
        b = j >> 4; bx = (j & 15) & 3; by = (j & 15) >> 2;
    }
    int w = threadIdx.x >> 6, l = threadIdx.x & 63;
    int lr = l & 15, lk = (l >> 4) * 8;
    int rowBase = bx * 64 + (w >> 1) * 32;
    int colBase = by * 64 + (w & 1) * 32;
    const ushort_t* xb = x + (size_t)b * n * 256;

    f32x4 acc[2][2] = {};
#pragma unroll 2
    for (int kk = 0; kk < 256; kk += 32) {
        s16x8 a[2], bb[2];
#pragma unroll
        for (int i = 0; i < 2; ++i)
            a[i] = *reinterpret_cast<const s16x8*>(xb + (size_t)(rowBase + i * 16 + lr) * 256 + kk + lk);
#pragma unroll
        for (int j = 0; j < 2; ++j)
            bb[j] = *reinterpret_cast<const s16x8*>(xb + (size_t)(colBase + j * 16 + lr) * 256 + kk + lk);
#pragma unroll
        for (int i = 0; i < 2; ++i)
#pragma unroll
            for (int j = 0; j < 2; ++j)
                acc[i][j] = MFMA16(a[i], bb[j], acc[i][j]);
    }
    float* ab = att + (size_t)b * n * n;
#pragma unroll
    for (int i = 0; i < 2; ++i)
#pragma unroll
        for (int j = 0; j < 2; ++j)
#pragma unroll
            for (int q = 0; q < 4; ++q) {
                int r = rowBase + i * 16 + (l >> 4) * 4 + q;
                int c = colBase + j * 16 + lr;
                ab[(size_t)r * n + c] = acc[i][j][q];
            }
}

// ---- fused attention: S = sigmoid(a1*x1x1^T + a2*up4(att2) + a3*up16(att3)); out = x1 + S*x1 ----
// wave = 16 Q-rows; loop over mm in 32-chunks; S^T via swapped MFMA so lane&15 = Q-row;
// shuffle-repack to PV A-frag; PV from x1t. No attb materialization.
__global__ __launch_bounds__(256) void k_attpv(
    const ushort_t* __restrict__ x1b, const ushort_t* __restrict__ x1t,
    const float* __restrict__ att2, const float* __restrict__ att3,
    const float* __restrict__ a1p, const float* __restrict__ a2p,
    const float* __restrict__ a3p, float* __restrict__ out)
{
    int b = blockIdx.y;
    int w = threadIdx.x >> 6, l = threadIdx.x & 63;
    int idx = l & 15, g = l >> 4;
    int rowBase = blockIdx.x * 64 + w * 16;
    const ushort_t* X = x1b + (size_t)b * N1 * C1;   // [1024][256]
    const ushort_t* V = x1t + (size_t)b * C1 * N1;   // [256][1024]

    // preload this wave's Q-row fragments (16 rows x K=256)
    s16x8 rf[8];
    const ushort_t* rowp = X + (size_t)(rowBase + idx) * 256 + g * 8;
#pragma unroll
    for (int ks = 0; ks < 8; ++ks) rf[ks] = *reinterpret_cast<const s16x8*>(rowp + ks * 32);

    // per-lane row-bilinear constants (nn fixed per lane)
    int nn = rowBase + idx;
    const float* A2 = att2 + (size_t)b * N2 * N2;
    const float* A3 = att3 + (size_t)b * N3 * N3;
    int r2l = nn >> 2; int r2h = min(r2l + 1, N2 - 1); float fr2 = (float)(nn & 3) * 0.25f;
    const float* A2lo = A2 + r2l * N2; const float* A2hi = A2 + r2h * N2;
    int r3l = nn >> 4; int r3h = min(r3l + 1, N3 - 1); float fr3 = (float)(nn & 15) * 0.0625f;
    const float* A3lo = A3 + r3l * N3; const float* A3hi = A3 + r3h * N3;
    float a1 = *a1p, a2 = *a2p, a3 = *a3p;

    f32x4 acc[16] = {};   // out[16 rows][256 cols]

    for (int mm0 = 0; mm0 < N1; mm0 += 32) {
        // S^T fragments: t0 covers mm0..mm0+16, t1 covers mm0+16..mm0+32
        f32x4 t0 = {}, t1 = {};
        const ushort_t* c0 = X + (size_t)(mm0 + idx) * 256 + g * 8;
        const ushort_t* c1 = c0 + 16 * 256;
#pragma unroll
        for (int ks = 0; ks < 8; ++ks) {
            s16x8 ca = *reinterpret_cast<const s16x8*>(c0 + ks * 32);
            s16x8 cb = *reinterpret_cast<const s16x8*>(c1 + ks * 32);
            t0 = MFMA16(ca, rf[ks], t0);
            t1 = MFMA16(cb, rf[ks], t1);
        }
        // hoisted bilinear taps: per frag, att2 col indices constant; att3 constant per chunk
        int c2a = (mm0 >> 2) + g;        int c2ah = min(c2a + 1, N2 - 1);
        int c2b = ((mm0 + 16) >> 2) + g; int c2bh = min(c2b + 1, N2 - 1);
        float p00 = A2lo[c2a], p01 = A2lo[c2ah], p10 = A2hi[c2a], p11 = A2hi[c2ah];
        float q00 = A2lo[c2b], q01 = A2lo[c2bh], q10 = A2hi[c2b], q11 = A2hi[c2bh];
        int c3a = mm0 >> 4; int c3ah = min(c3a + 1, N3 - 1); int c3bh = min(c3a + 2, N3 - 1);
        float s00 = A3lo[c3a], s01 = A3lo[c3ah], s10 = A3hi[c3a], s11 = A3hi[c3ah];
        float u01 = A3lo[c3bh], u11 = A3hi[c3bh];
#pragma unroll
        for (int r = 0; r < 4; ++r) {
            float fc2 = (float)r * 0.25f;
            float fc3 = (float)(g * 4 + r) * 0.0625f;
            // frag0
            float e0 = p00 + fc2 * (p01 - p00), e1 = p10 + fc2 * (p11 - p10);
            float v2 = e0 + fr2 * (e1 - e0);
            float f0 = s00 + fc3 * (s01 - s00), f1v = s10 + fc3 * (s11 - s10);
            float v3 = f0 + fr3 * (f1v - f0);
            float s = a1 * t0[r] + a2 * v2 + a3 * v3;
            t0[r] = 1.f / (1.f + __expf(-s));
            // frag1 (same fc2/fc3; shifted taps)
            e0 = q00 + fc2 * (q01 - q00); e1 = q10 + fc2 * (q11 - q10);
            v2 = e0 + fr2 * (e1 - e0);
            f0 = s01 + fc3 * (u01 - s01); f1v = s11 + fc3 * (u11 - s11);
            v3 = f0 + fr3 * (f1v - f0);
            s = a1 * t1[r] + a2 * v2 + a3 * v3;
            t1[r] = 1.f / (1.f + __expf(-s));
        }
        // repack S^T frags -> PV A-frag: lane (g,idx) element j = S[nn][mm0+g*8+j]
        // j: half=j>>2, r=j&3; src lane = ((2g+half)&3)*16+idx; frag = (g>=2) ? t1 : t0
        int base0 = ((2 * g) & 3) * 16 + idx;
        int base1 = ((2 * g + 1) & 3) * 16 + idx;
        bool hi = g >= 2;
        s16x8 pa;
#pragma unroll
        for (int r = 0; r < 4; ++r) {
            float v00 = __shfl(t0[r], base0); float v10 = __shfl(t1[r], base0);
            float v01 = __shfl(t0[r], base1); float v11 = __shfl(t1[r], base1);
            pa[r]     = (short)f2b(hi ? v10 : v00);
            pa[4 + r] = (short)f2b(hi ? v11 : v01);
        }
        // PV: acc[cf] += S[16 x 32] * V[32 x 256-cols]
        const ushort_t* vp = V + (size_t)idx * N1 + mm0 + g * 8;
#pragma unroll
        for (int cf = 0; cf < 16; ++cf) {
            s16x8 bv = *reinterpret_cast<const s16x8*>(vp + (size_t)cf * 16 * N1);
            acc[cf] = MFMA16(pa, bv, acc[cf]);
        }
    }
    // epilogue: out = bf16(p1) + acc
#pragma unroll
    for (int cf = 0; cf < 16; ++cf) {
#pragma unroll
        for (int q = 0; q < 4; ++q) {
            int r = rowBase + g * 4 + q;
            int c = cf * 16 + idx;
            size_t o = ((size_t)b * N1 + r) * C1 + c;
            out[o] = b2f(X[(size_t)r * 256 + c]) + acc[cf][q];
        }
    }
}

extern "C" void kernel_launch(void* const* d_in, const int* in_sizes, int n_in,
                              void* d_out, int out_size, void* d_ws, size_t ws_size,
                              hipStream_t stream) {
    const float* f1 = (const float*)d_in[0];
    const float* f2 = (const float*)d_in[1];
    const float* f3 = (const float*)d_in[2];
    const float* w1 = (const float*)d_in[3];
    const float* b1 = (const float*)d_in[4];
    const float* w2 = (const float*)d_in[5];
    const float* b2 = (const float*)d_in[6];
    const float* w3 = (const float*)d_in[7];
    const float* b3 = (const float*)d_in[8];
    const float* a1 = (const float*)d_in[9];
    const float* a2 = (const float*)d_in[10];
    const float* a3 = (const float*)d_in[11];

    char* ws = (char*)d_ws;
    size_t off = 0;
    auto alloc = [&](size_t bytes) -> void* {
        void* p = ws + off;
        off += (bytes + 255) & ~(size_t)255;
        return p;
    };
    ushort_t* w1t = (ushort_t*)alloc((size_t)256 * 256 * 2);
    ushort_t* w2t = (ushort_t*)alloc((size_t)256 * 512 * 2);
    ushort_t* w3t = (ushort_t*)alloc((size_t)256 * 1024 * 2);
    ushort_t* x1b = (ushort_t*)alloc((size_t)BATCH * N1 * C1 * 2);
    ushort_t* x1t = (ushort_t*)alloc((size_t)BATCH * N1 * C1 * 2);
    ushort_t* x2b = (ushort_t*)alloc((size_t)BATCH * N2 * C1 * 2);
    ushort_t* x3b = (ushort_t*)alloc((size_t)BATCH * N3 * C1 * 2);
    float*    att2 = (float*)alloc((size_t)BATCH * N2 * N2 * 4);
    float*    att3 = (float*)alloc((size_t)BATCH * N3 * N3 * 4);

    k_wt<<<(65536 + 131072 + 262144 + 255) / 256, 256, 0, stream>>>(w1, w2, w3, w1t, w2t, w3t);

    k_proj<<<PB3 + PB2 + PB1, 256, 0, stream>>>(f1, f2, f3, w1t, w2t, w3t,
                                                b1, b2, b3, x1b, x1t, x2b, x3b);

    k_xxt<<<16 + 256, 256, 0, stream>>>(x2b, x3b, att2, att3);

    k_attpv<<<dim3(16, BATCH), 256, 0, stream>>>(x1b, x1t, att2, att3,
                                                 a1, a2, a3, (float*)d_out);
}